// Round 3
// baseline (777.934 us; speedup 1.0000x reference)
//
#include <hip/hip_runtime.h>
#include <hip/hip_cooperative_groups.h>

namespace cg = cooperative_groups;

#define T       256
#define BSHIFT  12
#define BSIZE   4096            // nodes per bucket
#define MAXNB   32              // max buckets (N<=131072)
#define MM      32              // accumulate slices per bucket
#define EPB     4096            // edges per scatter tile
#define EPT     (EPB / T)       // 16 edges per thread
#define CAP     212992          // record capacity per bucket (expected 204.8k + margin)

// One cooperative kernel, 7 phases separated by grid.sync():
//   P0 scatter (atomic bucket allocation, no count/scan kernels)
//   P1 degree accumulate   P2 dinv + p
//   P3 layer1 accumulate   P4 mlp -> q
//   P5 layer2 accumulate   P6 output
__global__ __launch_bounds__(T, 4) void k_all(
        const int* __restrict__ row, const int* __restrict__ col,
        const float* __restrict__ w, const float* __restrict__ x,
        const float* __restrict__ W1, const float* __restrict__ b1,
        const float* __restrict__ W2, const float* __restrict__ b2,
        int2* __restrict__ rec, float* __restrict__ part,
        float* __restrict__ dinv, float* __restrict__ p, float* __restrict__ q,
        int* __restrict__ gcnt, float* __restrict__ out,
        int E, int N, int nb, int eb) {
    cg::grid_group grid = cg::this_grid();

    __shared__ int2 buf[EPB];                 // 32 KB; aliased as acc[] in P1/3/5
    __shared__ int  rnk[MAXNB];
    __shared__ int  lofs[MAXNB + 1];
    __shared__ int  rbase[MAXNB];
    float* acc = (float*)buf;

    const int t = threadIdx.x;

    // ================= P0: scatter with atomic allocation =================
    for (int g = blockIdx.x; g < eb; g += gridDim.x) {
        if (t < MAXNB) rnk[t] = 0;
        __syncthreads();
        int base = g * EPB;
        bool full = (base + EPB <= E);
        int4 c0, c1, c2, c3;
        if (full) {
            c0 = *(const int4*)(col + base + (t + 0 * T) * 4);
            c1 = *(const int4*)(col + base + (t + 1 * T) * 4);
            c2 = *(const int4*)(col + base + (t + 2 * T) * 4);
            c3 = *(const int4*)(col + base + (t + 3 * T) * 4);
            atomicAdd(&rnk[c0.x >> BSHIFT], 1); atomicAdd(&rnk[c0.y >> BSHIFT], 1);
            atomicAdd(&rnk[c0.z >> BSHIFT], 1); atomicAdd(&rnk[c0.w >> BSHIFT], 1);
            atomicAdd(&rnk[c1.x >> BSHIFT], 1); atomicAdd(&rnk[c1.y >> BSHIFT], 1);
            atomicAdd(&rnk[c1.z >> BSHIFT], 1); atomicAdd(&rnk[c1.w >> BSHIFT], 1);
            atomicAdd(&rnk[c2.x >> BSHIFT], 1); atomicAdd(&rnk[c2.y >> BSHIFT], 1);
            atomicAdd(&rnk[c2.z >> BSHIFT], 1); atomicAdd(&rnk[c2.w >> BSHIFT], 1);
            atomicAdd(&rnk[c3.x >> BSHIFT], 1); atomicAdd(&rnk[c3.y >> BSHIFT], 1);
            atomicAdd(&rnk[c3.z >> BSHIFT], 1); atomicAdd(&rnk[c3.w >> BSHIFT], 1);
        } else {
            for (int k = 0; k < EPT; ++k) {
                int e = base + t + k * T;
                if (e < E) atomicAdd(&rnk[col[e] >> BSHIFT], 1);
            }
        }
        __syncthreads();
        // exclusive scan of rnk (nb<=32, valid on lanes 0..31) + global alloc
        if (t < 64) {
            int v = (t < nb) ? rnk[t] : 0;
            int inc = v;
#pragma unroll
            for (int d = 1; d < 32; d <<= 1) {
                int o = __shfl_up(inc, d, 64);
                if (t >= d) inc += o;
            }
            if (t == 0) lofs[0] = 0;
            if (t < nb) {
                lofs[t + 1] = inc;
                rbase[t] = t * CAP + atomicAdd(&gcnt[t], v);
            }
        }
        __syncthreads();
        if (t < MAXNB) rnk[t] = 0;             // reuse as placement cursor
        __syncthreads();
        auto place = [&](int c, int r, float wv) {
            int b = c >> BSHIFT;
            int pos = lofs[b] + atomicAdd(&rnk[b], 1);
            buf[pos] = make_int2(((c & (BSIZE - 1)) << 17) | r, __float_as_int(wv));
        };
        if (full) {
            {
                int idx = base + (t + 0 * T) * 4;
                int4 r = *(const int4*)(row + idx);
                float4 wv = *(const float4*)(w + idx);
                place(c0.x, r.x, wv.x); place(c0.y, r.y, wv.y);
                place(c0.z, r.z, wv.z); place(c0.w, r.w, wv.w);
            }
            {
                int idx = base + (t + 1 * T) * 4;
                int4 r = *(const int4*)(row + idx);
                float4 wv = *(const float4*)(w + idx);
                place(c1.x, r.x, wv.x); place(c1.y, r.y, wv.y);
                place(c1.z, r.z, wv.z); place(c1.w, r.w, wv.w);
            }
            {
                int idx = base + (t + 2 * T) * 4;
                int4 r = *(const int4*)(row + idx);
                float4 wv = *(const float4*)(w + idx);
                place(c2.x, r.x, wv.x); place(c2.y, r.y, wv.y);
                place(c2.z, r.z, wv.z); place(c2.w, r.w, wv.w);
            }
            {
                int idx = base + (t + 3 * T) * 4;
                int4 r = *(const int4*)(row + idx);
                float4 wv = *(const float4*)(w + idx);
                place(c3.x, r.x, wv.x); place(c3.y, r.y, wv.y);
                place(c3.z, r.z, wv.z); place(c3.w, r.w, wv.w);
            }
        } else {
            for (int k = 0; k < EPT; ++k) {
                int e = base + t + k * T;
                if (e < E) place(col[e], row[e], w[e]);
            }
        }
        __syncthreads();
        // coalesced copy-out; bucket recovered monotonically from lofs
        int total = lofs[nb];
        int b = 0;
        for (int j = t; j < total; j += T) {
            while (j >= lofs[b + 1]) ++b;
            rec[rbase[b] + (j - lofs[b])] = buf[j];
        }
        __syncthreads();                        // buf/lofs/rbase reused next tile
    }
    grid.sync();

    // ================= accumulate phase helper =================
    auto acc_phase = [&](const float* __restrict__ src, bool has_src) {
        for (int s = blockIdx.x; s < nb * MM; s += gridDim.x) {
            int b = s / MM, m = s % MM;
            for (int j = t; j < BSIZE; j += T) acc[j] = 0.0f;
            __syncthreads();
            int s0 = b * CAP;
            int tb = gcnt[b];
            int chunk = ((tb + MM - 1) / MM + 7) & ~7;
            int lo = s0 + m * chunk;
            int hi = min(s0 + tb, lo + chunk);
            const int4* rec4 = (const int4*)rec;
            int i = lo + t * 8;
            for (; i + 7 < hi; i += T * 8) {
                int4 q0 = rec4[(i >> 1) + 0];
                int4 q1 = rec4[(i >> 1) + 1];
                int4 q2 = rec4[(i >> 1) + 2];
                int4 q3 = rec4[(i >> 1) + 3];
                float v0 = __int_as_float(q0.y), v1 = __int_as_float(q0.w);
                float v2 = __int_as_float(q1.y), v3 = __int_as_float(q1.w);
                float v4 = __int_as_float(q2.y), v5 = __int_as_float(q2.w);
                float v6 = __int_as_float(q3.y), v7 = __int_as_float(q3.w);
                if (has_src) {
                    v0 *= src[q0.x & 0x1FFFF]; v1 *= src[q0.z & 0x1FFFF];
                    v2 *= src[q1.x & 0x1FFFF]; v3 *= src[q1.z & 0x1FFFF];
                    v4 *= src[q2.x & 0x1FFFF]; v5 *= src[q2.z & 0x1FFFF];
                    v6 *= src[q3.x & 0x1FFFF]; v7 *= src[q3.z & 0x1FFFF];
                }
                atomicAdd(&acc[((unsigned)q0.x) >> 17], v0);
                atomicAdd(&acc[((unsigned)q0.z) >> 17], v1);
                atomicAdd(&acc[((unsigned)q1.x) >> 17], v2);
                atomicAdd(&acc[((unsigned)q1.z) >> 17], v3);
                atomicAdd(&acc[((unsigned)q2.x) >> 17], v4);
                atomicAdd(&acc[((unsigned)q2.z) >> 17], v5);
                atomicAdd(&acc[((unsigned)q3.x) >> 17], v6);
                atomicAdd(&acc[((unsigned)q3.z) >> 17], v7);
            }
            for (; i < hi; ++i) {               // tail owned by exactly one thread
                int2 r = rec[i];
                float v = __int_as_float(r.y);
                if (has_src) v *= src[r.x & 0x1FFFF];
                atomicAdd(&acc[((unsigned)r.x) >> 17], v);
            }
            __syncthreads();
            float* dst = part + (size_t)s * BSIZE;
            for (int j = t; j < BSIZE; j += T) dst[j] = acc[j];
            __syncthreads();
        }
    };

    auto reduceM = [&](int n) {
        int b = n >> BSHIFT, o = n & (BSIZE - 1);
        const float* pp = part + (size_t)b * MM * BSIZE + o;
        float sum = 0.0f;
#pragma unroll
        for (int m = 0; m < MM; ++m) sum += pp[(size_t)m * BSIZE];
        return sum;
    };

    // ================= P1: degree =================
    acc_phase(nullptr, false);
    grid.sync();

    // ================= P2: dinv + p =================
    for (int i = blockIdx.x * T + t; i < N; i += gridDim.x * T) {
        float d  = reduceM(i) + 1.0f;           // +1 = self-loop
        float di = rsqrtf(d);
        dinv[i] = di;
        p[i] = di * x[i];
    }
    grid.sync();

    // ================= P3: layer-1 accumulate =================
    acc_phase(p, true);
    grid.sync();

    // ================= P4: mlp -> q =================
    for (int i = blockIdx.x * T + t; i < N; i += gridDim.x * T) {
        float di = dinv[i];
        float s  = di * reduceM(i) + di * p[i];
        float a = 0.0f;
#pragma unroll
        for (int k = 0; k < 16; ++k) {
            float h = fmaxf(s * W1[k] + b1[k], 0.0f);
            a += h * W2[k];
        }
        q[i] = di * a;
    }
    grid.sync();

    // ================= P5: layer-2 accumulate =================
    acc_phase(q, true);
    grid.sync();

    // ================= P6: output =================
    for (int i = blockIdx.x * T + t; i < N; i += gridDim.x * T) {
        float di = dinv[i];
        out[i] = di * reduceM(i) + di * q[i] + b2[0];
    }
}

extern "C" void kernel_launch(void* const* d_in, const int* in_sizes, int n_in,
                              void* d_out, int out_size, void* d_ws, size_t ws_size,
                              hipStream_t stream) {
    const float* x  = (const float*)d_in[0];
    const int*   ei = (const int*)  d_in[1];
    const float* ew = (const float*)d_in[2];
    const float* W1 = (const float*)d_in[3];
    const float* b1 = (const float*)d_in[4];
    const float* W2 = (const float*)d_in[5];
    const float* b2 = (const float*)d_in[6];

    int N = in_sizes[0];             // x is [N,1]
    int E = in_sizes[2];             // edge_attr is [E]
    const int* row = ei;             // edge_index[0] = source
    const int* col = ei + E;         // edge_index[1] = target
    int nb = (N + BSIZE - 1) >> BSHIFT;          // 25
    int eb = (E + EPB - 1) / EPB;                // 1221

    // workspace layout (~57 MB), 256 B aligned
    char* wsp = (char*)d_ws;
    auto take = [&](size_t bytes) {
        char* r = wsp; wsp += (bytes + 255) & ~(size_t)255; return (void*)r;
    };
    int2*  rec  = (int2*) take((size_t)nb * CAP * 8);           // 42.6 MB
    float* part = (float*)take((size_t)nb * MM * BSIZE * 4);    // 13.1 MB
    float* dinv = (float*)take((size_t)N * 4);
    float* p    = (float*)take((size_t)N * 4);
    float* q    = (float*)take((size_t)N * 4);
    int*   gcnt = (int*)  take(MAXNB * 4);

    float* out = (float*)d_out;

    // co-resident grid sizing (one-time query, host-side only)
    static int grid_blocks = 0;
    if (grid_blocks == 0) {
        int occ = 0;
        (void)hipOccupancyMaxActiveBlocksPerMultiprocessor(&occ, (const void*)k_all, T, 0);
        if (occ < 1) occ = 1;
        hipDeviceProp_t props;
        int dev = 0;
        (void)hipGetDevice(&dev);
        (void)hipGetDeviceProperties(&props, dev);
        int cap = occ * props.multiProcessorCount;
        int want = nb * MM;                      // 800
        grid_blocks = cap < want ? cap : want;
        if (grid_blocks < 1) grid_blocks = 1;
    }

    (void)hipMemsetAsync(gcnt, 0, MAXNB * sizeof(int), stream);

    void* args[] = {
        (void*)&row, (void*)&col, (void*)&ew, (void*)&x,
        (void*)&W1, (void*)&b1, (void*)&W2, (void*)&b2,
        (void*)&rec, (void*)&part, (void*)&dinv, (void*)&p, (void*)&q,
        (void*)&gcnt, (void*)&out,
        (void*)&E, (void*)&N, (void*)&nb, (void*)&eb
    };
    (void)hipLaunchCooperativeKernel((const void*)k_all, dim3(grid_blocks), dim3(T),
                                     args, 0, stream);
}

// Round 6
// 256.760 us; speedup vs baseline: 3.0298x; 3.0298x over previous
//
#include <hip/hip_runtime.h>

#define T       256
#define BSHIFT  12
#define BSIZE   4096            // nodes per bucket
#define MAXNB   32              // max buckets (N<=131072)
#define MM      48              // accumulate slices per bucket
#define EPB     2048            // edges per scatter tile (16.5 KB LDS -> 8 blocks/CU)
#define EPT     (EPB / T)       // 8 edges per thread
#define CAP     212992          // record capacity per bucket (expected 204.8k + 18 sigma), %8==0

typedef int   i4 __attribute__((ext_vector_type(4)));
typedef int   i2 __attribute__((ext_vector_type(2)));
typedef float f4 __attribute__((ext_vector_type(4)));

// ---------- scatter: atomic bucket allocation (no count/scan pre-pass) ----------
// record.x = (col & 4095) << 17 | row  (row < 2^17), record.y = bits(w)
__global__ __launch_bounds__(T) void k_scatter(
        const int* __restrict__ row, const int* __restrict__ col,
        const float* __restrict__ w, int* __restrict__ gcnt,
        i2* __restrict__ rec, int E, int nb) {
    __shared__ i2  buf[EPB];                   // 16 KB
    __shared__ int rnk[MAXNB];
    __shared__ int lofs[MAXNB + 1];
    __shared__ int rbase[MAXNB];
    int t = threadIdx.x, g = blockIdx.x;
    if (t < MAXNB) rnk[t] = 0;
    __syncthreads();
    int base = g * EPB;
    bool full = (base + EPB <= E);
    i4 c0, c1;
    if (full) {
        c0 = __builtin_nontemporal_load((const i4*)(col + base + (t + 0 * T) * 4));
        c1 = __builtin_nontemporal_load((const i4*)(col + base + (t + 1 * T) * 4));
        atomicAdd(&rnk[c0.x >> BSHIFT], 1); atomicAdd(&rnk[c0.y >> BSHIFT], 1);
        atomicAdd(&rnk[c0.z >> BSHIFT], 1); atomicAdd(&rnk[c0.w >> BSHIFT], 1);
        atomicAdd(&rnk[c1.x >> BSHIFT], 1); atomicAdd(&rnk[c1.y >> BSHIFT], 1);
        atomicAdd(&rnk[c1.z >> BSHIFT], 1); atomicAdd(&rnk[c1.w >> BSHIFT], 1);
    } else {
        for (int k = 0; k < EPT; ++k) {
            int e = base + t + k * T;
            if (e < E) atomicAdd(&rnk[col[e] >> BSHIFT], 1);
        }
    }
    __syncthreads();
    // exclusive scan of rnk (nb<=32, lanes 0..31 of wave 0) + global bucket alloc
    if (t < 64) {
        int v = (t < nb) ? rnk[t] : 0;
        int inc = v;
#pragma unroll
        for (int d = 1; d < 32; d <<= 1) {
            int o = __shfl_up(inc, d, 64);
            if (t >= d) inc += o;
        }
        if (t == 0) lofs[0] = 0;
        if (t < nb) {
            lofs[t + 1] = inc;
            rbase[t] = t * CAP + atomicAdd(&gcnt[t], v);
        }
    }
    __syncthreads();
    if (t < MAXNB) rnk[t] = 0;                 // reuse as placement cursor
    __syncthreads();
    auto place = [&](int c, int r, float wv) {
        int b = c >> BSHIFT;
        int pos = lofs[b] + atomicAdd(&rnk[b], 1);
        i2 v;
        v.x = ((c & (BSIZE - 1)) << 17) | r;
        v.y = __float_as_int(wv);
        buf[pos] = v;
    };
    if (full) {
        {
            int idx = base + (t + 0 * T) * 4;
            i4 r  = __builtin_nontemporal_load((const i4*)(row + idx));
            f4 wv = __builtin_nontemporal_load((const f4*)(w + idx));
            place(c0.x, r.x, wv.x); place(c0.y, r.y, wv.y);
            place(c0.z, r.z, wv.z); place(c0.w, r.w, wv.w);
        }
        {
            int idx = base + (t + 1 * T) * 4;
            i4 r  = __builtin_nontemporal_load((const i4*)(row + idx));
            f4 wv = __builtin_nontemporal_load((const f4*)(w + idx));
            place(c1.x, r.x, wv.x); place(c1.y, r.y, wv.y);
            place(c1.z, r.z, wv.z); place(c1.w, r.w, wv.w);
        }
    } else {
        for (int k = 0; k < EPT; ++k) {
            int e = base + t + k * T;
            if (e < E) place(col[e], row[e], w[e]);
        }
    }
    __syncthreads();
    // coalesced copy-out; bucket recovered monotonically from lofs
    int total = lofs[nb];
    int b = 0;
    for (int j = t; j < total; j += T) {
        while (j >= lofs[b + 1]) ++b;
        __builtin_nontemporal_store(buf[j], &rec[rbase[b] + (j - lofs[b])]);
    }
}

// ---------- accumulate: LDS scatter-add of one bucket slice ----------
template <bool HAS_SRC>
__global__ __launch_bounds__(T) void k_acc(
        const i2* __restrict__ rec, const int* __restrict__ gcnt,
        const float* __restrict__ src, float* __restrict__ part) {
    __shared__ float acc[BSIZE];               // 16 KB
    int t = threadIdx.x, g = blockIdx.x;
    int b = g / MM, m = g % MM;
    f4* acc4 = (f4*)acc;
    for (int j = t; j < BSIZE / 4; j += T) acc4[j] = (f4){0.f, 0.f, 0.f, 0.f};
    __syncthreads();
    int s0 = b * CAP;
    int tb = gcnt[b];
    int chunk = ((tb + MM - 1) / MM + 7) & ~7;  // x8 records per slice
    int lo = s0 + m * chunk;
    int hi = min(s0 + tb, lo + chunk);
    const i4* rec4 = (const i4*)rec;
    int i = lo + t * 8;
    for (; i + 7 < hi; i += T * 8) {
        i4 q0 = __builtin_nontemporal_load(rec4 + (i >> 1) + 0);
        i4 q1 = __builtin_nontemporal_load(rec4 + (i >> 1) + 1);
        i4 q2 = __builtin_nontemporal_load(rec4 + (i >> 1) + 2);
        i4 q3 = __builtin_nontemporal_load(rec4 + (i >> 1) + 3);
        float v0 = __int_as_float(q0.y), v1 = __int_as_float(q0.w);
        float v2 = __int_as_float(q1.y), v3 = __int_as_float(q1.w);
        float v4 = __int_as_float(q2.y), v5 = __int_as_float(q2.w);
        float v6 = __int_as_float(q3.y), v7 = __int_as_float(q3.w);
        if (HAS_SRC) {
            v0 *= src[q0.x & 0x1FFFF]; v1 *= src[q0.z & 0x1FFFF];
            v2 *= src[q1.x & 0x1FFFF]; v3 *= src[q1.z & 0x1FFFF];
            v4 *= src[q2.x & 0x1FFFF]; v5 *= src[q2.z & 0x1FFFF];
            v6 *= src[q3.x & 0x1FFFF]; v7 *= src[q3.z & 0x1FFFF];
        }
        atomicAdd(&acc[((unsigned)q0.x) >> 17], v0);
        atomicAdd(&acc[((unsigned)q0.z) >> 17], v1);
        atomicAdd(&acc[((unsigned)q1.x) >> 17], v2);
        atomicAdd(&acc[((unsigned)q1.z) >> 17], v3);
        atomicAdd(&acc[((unsigned)q2.x) >> 17], v4);
        atomicAdd(&acc[((unsigned)q2.z) >> 17], v5);
        atomicAdd(&acc[((unsigned)q3.x) >> 17], v6);
        atomicAdd(&acc[((unsigned)q3.z) >> 17], v7);
    }
    for (; i < hi; ++i) {                      // tail owned by exactly one thread
        i2 r = rec[i];
        float v = __int_as_float(r.y);
        if (HAS_SRC) v *= src[r.x & 0x1FFFF];
        atomicAdd(&acc[((unsigned)r.x) >> 17], v);
    }
    __syncthreads();
    f4* dst4 = (f4*)(part + (size_t)g * BSIZE);
    for (int j = t; j < BSIZE / 4; j += T)
        __builtin_nontemporal_store(acc4[j], dst4 + j);
}

// ---------- reduce + pointwise ----------
__device__ __forceinline__ float reduceM(const float* __restrict__ part, int n) {
    int b = n >> BSHIFT, o = n & (BSIZE - 1);
    const float* pp = part + (size_t)b * MM * BSIZE + o;
    float s = 0.0f;
#pragma unroll
    for (int m = 0; m < MM; ++m) s += pp[(size_t)m * BSIZE];
    return s;
}

__global__ void k_red_dinv(const float* __restrict__ part, const float* __restrict__ x,
                           float* __restrict__ dinv, float* __restrict__ p, int N) {
    int i = blockIdx.x * blockDim.x + threadIdx.x;
    if (i < N) {
        float d  = reduceM(part, i) + 1.0f;     // +1 = self-loop
        float di = rsqrtf(d);
        dinv[i] = di;
        p[i] = di * x[i];
    }
}

__global__ void k_red_mlp(const float* __restrict__ part, const float* __restrict__ dinv,
                          const float* __restrict__ p,
                          const float* __restrict__ W1, const float* __restrict__ b1,
                          const float* __restrict__ W2,
                          float* __restrict__ q, int N) {
    int i = blockIdx.x * blockDim.x + threadIdx.x;
    if (i < N) {
        float di = dinv[i];
        float s  = di * reduceM(part, i) + di * p[i];
        float acc = 0.0f;
#pragma unroll
        for (int k = 0; k < 16; ++k) {
            float h = fmaxf(s * W1[k] + b1[k], 0.0f);
            acc += h * W2[k];
        }
        q[i] = di * acc;
    }
}

__global__ void k_red_out(const float* __restrict__ part, const float* __restrict__ dinv,
                          const float* __restrict__ q, const float* __restrict__ b2,
                          float* __restrict__ out, int N) {
    int i = blockIdx.x * blockDim.x + threadIdx.x;
    if (i < N) {
        float di = dinv[i];
        out[i] = di * reduceM(part, i) + di * q[i] + b2[0];
    }
}

extern "C" void kernel_launch(void* const* d_in, const int* in_sizes, int n_in,
                              void* d_out, int out_size, void* d_ws, size_t ws_size,
                              hipStream_t stream) {
    const float* x  = (const float*)d_in[0];
    const int*   ei = (const int*)  d_in[1];
    const float* ew = (const float*)d_in[2];
    const float* W1 = (const float*)d_in[3];
    const float* b1 = (const float*)d_in[4];
    const float* W2 = (const float*)d_in[5];
    const float* b2 = (const float*)d_in[6];

    const int N = in_sizes[0];       // x is [N,1]
    const int E = in_sizes[2];       // edge_attr is [E]
    const int* row = ei;             // edge_index[0] = source
    const int* col = ei + E;         // edge_index[1] = target
    const int nb = (N + BSIZE - 1) >> BSHIFT;    // 25
    const int eb = (E + EPB - 1) / EPB;          // 2442

    // workspace layout (~64 MB), 256 B aligned
    char* wsp = (char*)d_ws;
    auto take = [&](size_t bytes) {
        char* r = wsp; wsp += (bytes + 255) & ~(size_t)255; return (void*)r;
    };
    i2*    rec  = (i2*)   take((size_t)nb * CAP * 8);           // 42.6 MB
    float* part = (float*)take((size_t)nb * MM * BSIZE * 4);    // 19.7 MB
    float* dinv = (float*)take((size_t)N * 4);
    float* p    = (float*)take((size_t)N * 4);
    float* q    = (float*)take((size_t)N * 4);
    int*   gcnt = (int*)  take(MAXNB * 4);

    float* out = (float*)d_out;

    const int nbk = (N + T - 1) / T;             // 391
    const int ab  = nb * MM;                     // 1200

    (void)hipMemsetAsync(gcnt, 0, MAXNB * sizeof(int), stream);

    k_scatter<<<eb, T, 0, stream>>>(row, col, ew, gcnt, rec, E, nb);

    // degree
    k_acc<false><<<ab, T, 0, stream>>>(rec, gcnt, nullptr, part);
    k_red_dinv  <<<nbk, T, 0, stream>>>(part, x, dinv, p, N);

    // layer 1
    k_acc<true><<<ab, T, 0, stream>>>(rec, gcnt, p, part);
    k_red_mlp  <<<nbk, T, 0, stream>>>(part, dinv, p, W1, b1, W2, q, N);

    // layer 2
    k_acc<true><<<ab, T, 0, stream>>>(rec, gcnt, q, part);
    k_red_out  <<<nbk, T, 0, stream>>>(part, dinv, q, b2, out, N);
}